// Round 18
// baseline (992.049 us; speedup 1.0000x reference)
//
#include <hip/hip_runtime.h>
#include <math.h>

#define M_TOTAL 8192
#define N_RFF   4096
#define K_DIM   512
#define TOPK    409

#define BM 128
#define BN 128
#define BK 16
#define LDSV (BM + 4)   // 132 floats = 528 B row stride (16B-aligned)
#define NT   (K_DIM / BK)

// ---------------------------------------------------------------------------
// GEMM: theta[r][c] = SINGLE ascending-k f32 fmaf chain over k=0..511
// (bit-frozen reference semantics). 128x128 tile, 8x8 acc/thread (4+4 split).
// Ping-pong LDS double-buffer, one barrier per k-tile, async stage split.
// s = theta + b (f32); z = (float)cos((double)s) * f32(SCALE).
// ---------------------------------------------------------------------------
__global__ __launch_bounds__(256) void rff_gemm_chain(
    const float* __restrict__ x, const float* __restrict__ W,
    const float* __restrict__ bias, float* __restrict__ zbuf,
    int m0, int rows)
{
    __shared__ float As[2][BK][LDSV];
    __shared__ float Bs[2][BK][LDSV];

    const int tid = threadIdx.x;
    const int bm = blockIdx.y * BM, bn = blockIdx.x * BN;
    const int tx = tid & 15, ty = tid >> 4;

    const int r0 = tid >> 2, q = tid & 3;
    const int r1 = r0 + 64;
    int gr0 = m0 + bm + r0; if (gr0 > M_TOTAL - 1) gr0 = M_TOTAL - 1;
    int gr1 = m0 + bm + r1; if (gr1 > M_TOTAL - 1) gr1 = M_TOTAL - 1;
    const float* pa0 = x + (size_t)gr0 * K_DIM + q * 4;
    const float* pa1 = x + (size_t)gr1 * K_DIM + q * 4;
    const float* pb0 = W + (size_t)(bn + r0) * K_DIM + q * 4;
    const float* pb1 = W + (size_t)(bn + r1) * K_DIM + q * 4;

    float acc[8][8];
    #pragma unroll
    for (int i = 0; i < 8; ++i)
        #pragma unroll
        for (int j = 0; j < 8; ++j) acc[i][j] = 0.0f;

    {   // prologue: stage tile 0 into buffer 0
        const float4 a0 = *(const float4*)(pa0);
        const float4 a1 = *(const float4*)(pa1);
        const float4 b0 = *(const float4*)(pb0);
        const float4 b1 = *(const float4*)(pb1);
        As[0][q*4+0][r0] = a0.x; As[0][q*4+1][r0] = a0.y;
        As[0][q*4+2][r0] = a0.z; As[0][q*4+3][r0] = a0.w;
        As[0][q*4+0][r1] = a1.x; As[0][q*4+1][r1] = a1.y;
        As[0][q*4+2][r1] = a1.z; As[0][q*4+3][r1] = a1.w;
        Bs[0][q*4+0][r0] = b0.x; Bs[0][q*4+1][r0] = b0.y;
        Bs[0][q*4+2][r0] = b0.z; Bs[0][q*4+3][r0] = b0.w;
        Bs[0][q*4+0][r1] = b1.x; Bs[0][q*4+1][r1] = b1.y;
        Bs[0][q*4+2][r1] = b1.z; Bs[0][q*4+3][r1] = b1.w;
    }
    __syncthreads();

    for (int t = 0; t < NT; ++t) {
        const int cur = t & 1;
        float4 a0, a1, b0, b1;
        const bool more = (t + 1 < NT);
        if (more) {                         // issue next-tile loads EARLY
            const int ko = (t + 1) * BK;
            a0 = *(const float4*)(pa0 + ko);
            a1 = *(const float4*)(pa1 + ko);
            b0 = *(const float4*)(pb0 + ko);
            b1 = *(const float4*)(pb1 + ko);
        }

        const float (*Ac)[LDSV] = As[cur];
        const float (*Bc)[LDSV] = Bs[cur];
        #pragma unroll
        for (int k = 0; k < BK; ++k) {
            float a[8], b[8];
            #pragma unroll
            for (int i = 0; i < 4; ++i) {
                a[i]     = Ac[k][ty * 4 + i];
                a[4 + i] = Ac[k][64 + ty * 4 + i];
            }
            #pragma unroll
            for (int j = 0; j < 4; ++j) {
                b[j]     = Bc[k][tx * 4 + j];
                b[4 + j] = Bc[k][64 + tx * 4 + j];
            }
            #pragma unroll
            for (int i = 0; i < 8; ++i)
                #pragma unroll
                for (int j = 0; j < 8; ++j)
                    acc[i][j] = fmaf(a[i], b[j], acc[i][j]);
        }

        if (more) {
            const int nxt = cur ^ 1;
            As[nxt][q*4+0][r0] = a0.x; As[nxt][q*4+1][r0] = a0.y;
            As[nxt][q*4+2][r0] = a0.z; As[nxt][q*4+3][r0] = a0.w;
            As[nxt][q*4+0][r1] = a1.x; As[nxt][q*4+1][r1] = a1.y;
            As[nxt][q*4+2][r1] = a1.z; As[nxt][q*4+3][r1] = a1.w;
            Bs[nxt][q*4+0][r0] = b0.x; Bs[nxt][q*4+1][r0] = b0.y;
            Bs[nxt][q*4+2][r0] = b0.z; Bs[nxt][q*4+3][r0] = b0.w;
            Bs[nxt][q*4+0][r1] = b1.x; Bs[nxt][q*4+1][r1] = b1.y;
            Bs[nxt][q*4+2][r1] = b1.z; Bs[nxt][q*4+3][r1] = b1.w;
            __syncthreads();
        }
    }

    const float SC32 = 0.0220970869f;   // f32(sqrt(2/4096)) = 0x3CB504F3

    #pragma unroll
    for (int i = 0; i < 8; ++i) {
        const int rloc = bm + ((i < 4) ? (ty * 4 + i) : (64 + ty * 4 + (i - 4)));
        if (rloc < rows) {
            float* zr = zbuf + (size_t)rloc * N_RFF + bn;
            #pragma unroll
            for (int j = 0; j < 8; ++j) {
                const int c = (j < 4) ? (tx * 4 + j) : (64 + tx * 4 + (j - 4));
                const float s = acc[i][j] + bias[bn + c];   // f32 bias add
                zr[c] = (float)cos((double)s) * SC32;       // CR f32 cos, f32 mul
            }
        }
    }
}

// ---------------------------------------------------------------------------
// Per-row exact top-K on f32 keys |z|, smallest-index tie-break
// (stable argsort-desc / lax.top_k semantics). VERBATIM r16 (proven, absmax 0.0).
// ---------------------------------------------------------------------------
__global__ __launch_bounds__(256) void topk_select(
    const float* __restrict__ zbuf, float* __restrict__ out, int m0)
{
    const int row = blockIdx.x;
    const int tid = threadIdx.x;
    const float* z = zbuf + (size_t)row * N_RFF;

    float v[16];
    unsigned int key[16];
    #pragma unroll
    for (int i = 0; i < 16; ++i) {
        v[i]   = z[tid + i * 256];
        key[i] = __float_as_uint(fabsf(v[i]));
    }

    __shared__ unsigned int hist[256];
    __shared__ unsigned int s_pref;
    __shared__ int s_k;
    __shared__ int tielist[64];
    __shared__ int tiecnt;
    __shared__ unsigned int keepbits[N_RFF / 32];

    if (tid == 0) tiecnt = 0;
    if (tid < N_RFF / 32) keepbits[tid] = 0u;

    unsigned int prefix = 0u;
    int kneed = TOPK;

    for (int shift = 24; shift >= 0; shift -= 8) {
        hist[tid] = 0u;
        __syncthreads();
        const unsigned int pmask = (shift == 24) ? 0u : (0xFFFFFFFFu << (shift + 8));
        #pragma unroll
        for (int i = 0; i < 16; ++i)
            if ((key[i] & pmask) == prefix)
                atomicAdd(&hist[(key[i] >> shift) & 255u], 1u);
        __syncthreads();
        if (tid == 0) {
            unsigned int accum = 0; int d = 255;
            for (; d >= 0; --d) {
                const unsigned int c = hist[d];
                if (accum + c >= (unsigned)kneed) break;
                accum += c;
            }
            if (d < 0) d = 0;
            s_pref = prefix | ((unsigned int)d << shift);
            s_k = kneed - (int)accum;
        }
        __syncthreads();
        prefix = s_pref; kneed = s_k;
        __syncthreads();
    }

    const unsigned int thr = prefix;

    #pragma unroll
    for (int i = 0; i < 16; ++i) {
        if (key[i] == thr) {
            const int p = atomicAdd(&tiecnt, 1);
            if (p < 64) tielist[p] = tid + i * 256;
        }
    }
    __syncthreads();

    if (tid == 0) {
        int n = tiecnt; if (n > 64) n = 64;
        for (int a = 1; a < n; ++a) {
            const int vi = tielist[a];
            int b2 = a - 1;
            while (b2 >= 0 && tielist[b2] > vi) { tielist[b2 + 1] = tielist[b2]; --b2; }
            tielist[b2 + 1] = vi;
        }
        int t = kneed; if (t > n) t = n;
        for (int a = 0; a < t; ++a) {
            const int idx = tielist[a];
            keepbits[idx >> 5] |= (1u << (idx & 31));
        }
    }
    __syncthreads();

    float* orow = out + (size_t)(m0 + row) * N_RFF;
    #pragma unroll
    for (int i = 0; i < 16; ++i) {
        const int idx = tid + i * 256;
        const bool keep = (key[i] > thr) ||
                          (key[i] == thr && ((keepbits[idx >> 5] >> (idx & 31)) & 1u));
        orow[idx] = keep ? v[i] : 0.0f;
    }
}

// ---------------------------------------------------------------------------
extern "C" void kernel_launch(void* const* d_in, const int* in_sizes, int n_in,
                              void* d_out, int out_size, void* d_ws, size_t ws_size,
                              hipStream_t stream)
{
    const float* x    = (const float*)d_in[0];
    const float* W    = (const float*)d_in[1];
    const float* bias = (const float*)d_in[2];
    float* out  = (float*)d_out;
    float* zbuf = (float*)d_ws;

    const size_t row_bytes = (size_t)N_RFF * sizeof(float);
    const size_t maxrows   = row_bytes ? (ws_size / row_bytes) : 0;

    int chunk = (maxrows >= (size_t)M_TOTAL) ? M_TOTAL : (int)maxrows;
    if (chunk < 1) chunk = 1;

    for (int m0 = 0; m0 < M_TOTAL; m0 += chunk) {
        int rows = M_TOTAL - m0;
        if (rows > chunk) rows = chunk;
        dim3 gg(N_RFF / BN, (rows + BM - 1) / BM);
        hipLaunchKernelGGL(rff_gemm_chain, gg, dim3(256), 0, stream,
                           x, W, bias, zbuf, m0, rows);
        hipLaunchKernelGGL(topk_select, dim3(rows), dim3(256), 0, stream,
                           zbuf, out, m0);
    }
}

// Round 19
// 581.692 us; speedup vs baseline: 1.7055x; 1.7055x over previous
//
#include <hip/hip_runtime.h>
#include <math.h>

#define M_TOTAL 8192
#define N_RFF   4096
#define K_DIM   512
#define TOPK    409

#define BM 128
#define BN 128
#define BK 16
#define LDSV (BM + 4)   // 132 floats = 528 B row stride (16B-aligned)

// ---------------------------------------------------------------------------
// GEMM (VERBATIM r16 — proven 490us, 60 VGPR, absmax 0.0):
// theta = single ascending-k f32 fmaf chain; 128x128 tile, 8x8 acc/thread.
// s = theta + b (f32); z = (float)cos((double)s) * f32(SCALE).
// NOTE r18: explicit LDS double-buffering blew VGPR 60->184, occupancy
// 37->12%, 850us. Do NOT re-pipeline this kernel at source level.
// ---------------------------------------------------------------------------
__global__ __launch_bounds__(256) void rff_gemm_chain(
    const float* __restrict__ x, const float* __restrict__ W,
    const float* __restrict__ bias, float* __restrict__ zbuf,
    int m0, int rows)
{
    __shared__ float As[BK][LDSV];
    __shared__ float Bs[BK][LDSV];

    const int tid = threadIdx.x;
    const int bm = blockIdx.y * BM, bn = blockIdx.x * BN;
    const int tx = tid & 15, ty = tid >> 4;

    float acc[8][8];
    #pragma unroll
    for (int i = 0; i < 8; ++i)
        #pragma unroll
        for (int j = 0; j < 8; ++j) acc[i][j] = 0.0f;

    for (int kt = 0; kt < K_DIM; kt += BK) {
        #pragma unroll
        for (int it = 0; it < 2; ++it) {
            const int i = tid + it * 256;     // 0..511
            const int r = i >> 2;             // 0..127
            const int q = i & 3;              // k-quad
            int gr = m0 + bm + r;             // clamped read; write guarded
            if (gr > M_TOTAL - 1) gr = M_TOTAL - 1;
            const float4 va = *(const float4*)(x + (size_t)gr * K_DIM + kt + q * 4);
            As[q*4+0][r] = va.x;  As[q*4+1][r] = va.y;
            As[q*4+2][r] = va.z;  As[q*4+3][r] = va.w;
            const float4 vb = *(const float4*)(W + (size_t)(bn + r) * K_DIM + kt + q * 4);
            Bs[q*4+0][r] = vb.x;  Bs[q*4+1][r] = vb.y;
            Bs[q*4+2][r] = vb.z;  Bs[q*4+3][r] = vb.w;
        }
        __syncthreads();

        #pragma unroll
        for (int k = 0; k < BK; ++k) {
            float a[8], b[8];
            #pragma unroll
            for (int i = 0; i < 4; ++i) {
                a[i]     = As[k][ty * 4 + i];
                a[4 + i] = As[k][64 + ty * 4 + i];
            }
            #pragma unroll
            for (int j = 0; j < 4; ++j) {
                b[j]     = Bs[k][tx * 4 + j];
                b[4 + j] = Bs[k][64 + tx * 4 + j];
            }
            #pragma unroll
            for (int i = 0; i < 8; ++i)
                #pragma unroll
                for (int j = 0; j < 8; ++j)
                    acc[i][j] = fmaf(a[i], b[j], acc[i][j]);
        }
        __syncthreads();
    }

    const float SC32 = 0.0220970869f;   // f32(sqrt(2/4096)) = 0x3CB504F3

    #pragma unroll
    for (int i = 0; i < 8; ++i) {
        const int rloc = bm + ((i < 4) ? (ty * 4 + i) : (64 + ty * 4 + (i - 4)));
        if (rloc < rows) {
            float* zr = zbuf + (size_t)rloc * N_RFF + bn;
            #pragma unroll
            for (int j = 0; j < 8; ++j) {
                const int c = (j < 4) ? (tx * 4 + j) : (64 + tx * 4 + (j - 4));
                const float s = acc[i][j] + bias[bn + c];   // f32 bias add
                zr[c] = (float)cos((double)s) * SC32;       // CR f32 cos, f32 mul
            }
        }
    }
}

// ---------------------------------------------------------------------------
// Per-row exact top-K on f32 keys |z|, smallest-index tie-break.
// r16 structure; ONLY change: the tid==0 serial 256-iter digit scan is
// replaced by an LDS Hillis-Steele SUFFIX scan (8 steps, explicit barriers).
// Equivalence: serial accum = S[d]-h[d]; break condition accum+h>=kneed
// <=> S>=kneed && S-h<kneed; s_k = kneed-(S-h). Unique d (S monotone).
// ---------------------------------------------------------------------------
__global__ __launch_bounds__(256) void topk_select(
    const float* __restrict__ zbuf, float* __restrict__ out, int m0)
{
    const int row = blockIdx.x;
    const int tid = threadIdx.x;
    const float* z = zbuf + (size_t)row * N_RFF;

    float v[16];
    unsigned int key[16];
    #pragma unroll
    for (int i = 0; i < 16; ++i) {
        v[i]   = z[tid + i * 256];
        key[i] = __float_as_uint(fabsf(v[i]));
    }

    __shared__ unsigned int hist[256];
    __shared__ unsigned int scan[256];
    __shared__ unsigned int s_pref;
    __shared__ int s_k;
    __shared__ int tielist[64];
    __shared__ int tiecnt;
    __shared__ unsigned int keepbits[N_RFF / 32];

    if (tid == 0) tiecnt = 0;
    if (tid < N_RFF / 32) keepbits[tid] = 0u;

    unsigned int prefix = 0u;
    int kneed = TOPK;

    for (int shift = 24; shift >= 0; shift -= 8) {
        hist[tid] = 0u;
        __syncthreads();
        const unsigned int pmask = (shift == 24) ? 0u : (0xFFFFFFFFu << (shift + 8));
        #pragma unroll
        for (int i = 0; i < 16; ++i)
            if ((key[i] & pmask) == prefix)
                atomicAdd(&hist[(key[i] >> shift) & 255u], 1u);
        __syncthreads();

        const unsigned int h = hist[tid];
        scan[tid] = h;
        __syncthreads();
        // suffix scan: scan[d] = sum of h over digits >= d
        #pragma unroll
        for (int off = 1; off < 256; off <<= 1) {
            const unsigned int t2 = (tid + off < 256) ? scan[tid + off] : 0u;
            __syncthreads();
            scan[tid] += t2;
            __syncthreads();
        }
        const unsigned int S = scan[tid];
        if (S >= (unsigned)kneed && S - h < (unsigned)kneed) {  // unique digit
            s_pref = prefix | ((unsigned int)tid << shift);
            s_k    = kneed - (int)(S - h);
        }
        __syncthreads();
        prefix = s_pref; kneed = s_k;
        __syncthreads();
    }

    const unsigned int thr = prefix;

    #pragma unroll
    for (int i = 0; i < 16; ++i) {
        if (key[i] == thr) {
            const int p = atomicAdd(&tiecnt, 1);
            if (p < 64) tielist[p] = tid + i * 256;
        }
    }
    __syncthreads();

    if (tid == 0) {
        int n = tiecnt; if (n > 64) n = 64;
        for (int a = 1; a < n; ++a) {            // insertion sort ascending
            const int vi = tielist[a];
            int b2 = a - 1;
            while (b2 >= 0 && tielist[b2] > vi) { tielist[b2 + 1] = tielist[b2]; --b2; }
            tielist[b2 + 1] = vi;
        }
        int t = kneed; if (t > n) t = n;
        for (int a = 0; a < t; ++a) {
            const int idx = tielist[a];
            keepbits[idx >> 5] |= (1u << (idx & 31));
        }
    }
    __syncthreads();

    float* orow = out + (size_t)(m0 + row) * N_RFF;
    #pragma unroll
    for (int i = 0; i < 16; ++i) {
        const int idx = tid + i * 256;
        const bool keep = (key[i] > thr) ||
                          (key[i] == thr && ((keepbits[idx >> 5] >> (idx & 31)) & 1u));
        orow[idx] = keep ? v[i] : 0.0f;
    }
}

// ---------------------------------------------------------------------------
extern "C" void kernel_launch(void* const* d_in, const int* in_sizes, int n_in,
                              void* d_out, int out_size, void* d_ws, size_t ws_size,
                              hipStream_t stream)
{
    const float* x    = (const float*)d_in[0];
    const float* W    = (const float*)d_in[1];
    const float* bias = (const float*)d_in[2];
    float* out  = (float*)d_out;
    float* zbuf = (float*)d_ws;

    const size_t row_bytes = (size_t)N_RFF * sizeof(float);
    const size_t maxrows   = row_bytes ? (ws_size / row_bytes) : 0;

    int chunk = (maxrows >= (size_t)M_TOTAL) ? M_TOTAL : (int)maxrows;
    if (chunk < 1) chunk = 1;

    for (int m0 = 0; m0 < M_TOTAL; m0 += chunk) {
        int rows = M_TOTAL - m0;
        if (rows > chunk) rows = chunk;
        dim3 gg(N_RFF / BN, (rows + BM - 1) / BM);
        hipLaunchKernelGGL(rff_gemm_chain, gg, dim3(256), 0, stream,
                           x, W, bias, zbuf, m0, rows);
        hipLaunchKernelGGL(topk_select, dim3(rows), dim3(256), 0, stream,
                           zbuf, out, m0);
    }
}

// Round 20
// 502.076 us; speedup vs baseline: 1.9759x; 1.1586x over previous
//
#include <hip/hip_runtime.h>
#include <math.h>

#define M_TOTAL 8192
#define N_RFF   4096
#define K_DIM   512
#define TOPK    409

#define BM 128
#define BN 128
#define BK 16
#define LDSV (BM + 4)   // 132 floats = 528 B row stride (16B-aligned)

// ---------------------------------------------------------------------------
// GEMM (VERBATIM r16/r19 — proven 486us, 60 VGPR, absmax 0.0):
// theta = single ascending-k f32 fmaf chain; 128x128 tile, 8x8 acc/thread.
// s = theta + b (f32); z = (float)cos((double)s) * f32(SCALE).
// NOTE r18: explicit LDS double-buffering blew VGPR 60->184, occupancy
// 37->12%, 850us. Do NOT re-pipeline this kernel at source level.
// ---------------------------------------------------------------------------
__global__ __launch_bounds__(256) void rff_gemm_chain(
    const float* __restrict__ x, const float* __restrict__ W,
    const float* __restrict__ bias, float* __restrict__ zbuf,
    int m0, int rows)
{
    __shared__ float As[BK][LDSV];
    __shared__ float Bs[BK][LDSV];

    const int tid = threadIdx.x;
    const int bm = blockIdx.y * BM, bn = blockIdx.x * BN;
    const int tx = tid & 15, ty = tid >> 4;

    float acc[8][8];
    #pragma unroll
    for (int i = 0; i < 8; ++i)
        #pragma unroll
        for (int j = 0; j < 8; ++j) acc[i][j] = 0.0f;

    for (int kt = 0; kt < K_DIM; kt += BK) {
        #pragma unroll
        for (int it = 0; it < 2; ++it) {
            const int i = tid + it * 256;     // 0..511
            const int r = i >> 2;             // 0..127
            const int q = i & 3;              // k-quad
            int gr = m0 + bm + r;             // clamped read; write guarded
            if (gr > M_TOTAL - 1) gr = M_TOTAL - 1;
            const float4 va = *(const float4*)(x + (size_t)gr * K_DIM + kt + q * 4);
            As[q*4+0][r] = va.x;  As[q*4+1][r] = va.y;
            As[q*4+2][r] = va.z;  As[q*4+3][r] = va.w;
            const float4 vb = *(const float4*)(W + (size_t)(bn + r) * K_DIM + kt + q * 4);
            Bs[q*4+0][r] = vb.x;  Bs[q*4+1][r] = vb.y;
            Bs[q*4+2][r] = vb.z;  Bs[q*4+3][r] = vb.w;
        }
        __syncthreads();

        #pragma unroll
        for (int k = 0; k < BK; ++k) {
            float a[8], b[8];
            #pragma unroll
            for (int i = 0; i < 4; ++i) {
                a[i]     = As[k][ty * 4 + i];
                a[4 + i] = As[k][64 + ty * 4 + i];
            }
            #pragma unroll
            for (int j = 0; j < 4; ++j) {
                b[j]     = Bs[k][tx * 4 + j];
                b[4 + j] = Bs[k][64 + tx * 4 + j];
            }
            #pragma unroll
            for (int i = 0; i < 8; ++i)
                #pragma unroll
                for (int j = 0; j < 8; ++j)
                    acc[i][j] = fmaf(a[i], b[j], acc[i][j]);
        }
        __syncthreads();
    }

    const float SC32 = 0.0220970869f;   // f32(sqrt(2/4096)) = 0x3CB504F3

    #pragma unroll
    for (int i = 0; i < 8; ++i) {
        const int rloc = bm + ((i < 4) ? (ty * 4 + i) : (64 + ty * 4 + (i - 4)));
        if (rloc < rows) {
            float* zr = zbuf + (size_t)rloc * N_RFF + bn;
            #pragma unroll
            for (int j = 0; j < 8; ++j) {
                const int c = (j < 4) ? (tx * 4 + j) : (64 + tx * 4 + (j - 4));
                const float s = acc[i][j] + bias[bn + c];   // f32 bias add
                zr[c] = (float)cos((double)s) * SC32;       // CR f32 cos, f32 mul
            }
        }
    }
}

// ---------------------------------------------------------------------------
// Per-row exact top-K via SINGLE-PASS value buckets:
// bucket = trunc(|z| * 185000) in [0, 4089) — monotone in the f32 key, so
// all elements with bucket > b* are exactly the ones above the boundary
// bucket; the ~4 elements IN b* are resolved by exact f32 key (desc) with
// smallest-index ties (lax.top_k semantics). One histogram (4096 bins,
// low atomic contention), one suffix scan (r19-proven pattern), tiny sort.
// ---------------------------------------------------------------------------
#define NBUCKET 4096
#define BSCALE  185000.0f
#define CANDMAX 256

__global__ __launch_bounds__(256) void topk_select(
    const float* __restrict__ zbuf, float* __restrict__ out, int m0)
{
    const int row = blockIdx.x;
    const int tid = threadIdx.x;
    const float* z = zbuf + (size_t)row * N_RFF;

    float v[16];
    unsigned int key[16];
    int bkt[16];
    #pragma unroll
    for (int i = 0; i < 16; ++i) {
        v[i]   = z[tid + i * 256];
        const float av = fabsf(v[i]);
        key[i] = __float_as_uint(av);
        bkt[i] = (int)(av * BSCALE);     // 0..4088 (max |z| = SC32)
    }

    __shared__ unsigned int hist[NBUCKET];   // 16 KB
    __shared__ unsigned int scan[256];
    __shared__ int s_bstar;
    __shared__ int s_kneed;
    __shared__ unsigned int cand_key[CANDMAX];
    __shared__ unsigned int cand_idx[CANDMAX];
    __shared__ int cand_n;
    __shared__ unsigned int keepbits[N_RFF / 32];

    #pragma unroll
    for (int b = 0; b < NBUCKET / 256; ++b) hist[tid + b * 256] = 0u;
    if (tid == 0) cand_n = 0;
    if (tid < N_RFF / 32) keepbits[tid] = 0u;
    __syncthreads();

    #pragma unroll
    for (int i = 0; i < 16; ++i) atomicAdd(&hist[bkt[i]], 1u);
    __syncthreads();

    // thread-local suffix over its 16 contiguous buckets [tid*16 .. +15]
    unsigned int lh[16], ls[16];
    #pragma unroll
    for (int j = 0; j < 16; ++j) lh[j] = hist[tid * 16 + j];
    unsigned int run = 0;
    #pragma unroll
    for (int j = 15; j >= 0; --j) { run += lh[j]; ls[j] = run; }
    const unsigned int T = run;

    scan[tid] = T;
    __syncthreads();
    // block suffix scan (r19-proven): scan[t] = sum of T over t' >= t
    #pragma unroll
    for (int off = 1; off < 256; off <<= 1) {
        const unsigned int t2 = (tid + off < 256) ? scan[tid + off] : 0u;
        __syncthreads();
        scan[tid] += t2;
        __syncthreads();
    }
    const unsigned int Sexcl = scan[tid] - T;    // sum over threads > tid

    #pragma unroll
    for (int j = 0; j < 16; ++j) {
        const unsigned int S = Sexcl + ls[j];    // sum over buckets >= tid*16+j
        const unsigned int h = lh[j];
        if (S >= (unsigned)TOPK && S - h < (unsigned)TOPK) {  // unique bucket
            s_bstar = tid * 16 + j;
            s_kneed = TOPK - (int)(S - h);
        }
    }
    __syncthreads();
    const int bstar = s_bstar;
    const int kneed = s_kneed;

    // collect boundary-bucket candidates (expected ~4, capped 256)
    #pragma unroll
    for (int i = 0; i < 16; ++i) {
        if (bkt[i] == bstar) {
            const int p = atomicAdd(&cand_n, 1);
            if (p < CANDMAX) { cand_key[p] = key[i]; cand_idx[p] = tid + i * 256; }
        }
    }
    __syncthreads();

    if (tid == 0) {
        int n = cand_n; if (n > CANDMAX) n = CANDMAX;
        // insertion sort: key desc, idx asc (stable top-k order)
        for (int a = 1; a < n; ++a) {
            const unsigned int kk = cand_key[a], ii = cand_idx[a];
            int b2 = a - 1;
            while (b2 >= 0 && (cand_key[b2] < kk ||
                               (cand_key[b2] == kk && cand_idx[b2] > ii))) {
                cand_key[b2 + 1] = cand_key[b2];
                cand_idx[b2 + 1] = cand_idx[b2];
                --b2;
            }
            cand_key[b2 + 1] = kk; cand_idx[b2 + 1] = ii;
        }
        int t = kneed; if (t > n) t = n;
        for (int a = 0; a < t; ++a) {
            const unsigned int idx = cand_idx[a];
            keepbits[idx >> 5] |= (1u << (idx & 31));
        }
    }
    __syncthreads();

    float* orow = out + (size_t)(m0 + row) * N_RFF;
    #pragma unroll
    for (int i = 0; i < 16; ++i) {
        const int idx = tid + i * 256;
        const bool keep = (bkt[i] > bstar) ||
                          (bkt[i] == bstar &&
                           ((keepbits[idx >> 5] >> (idx & 31)) & 1u));
        orow[idx] = keep ? v[i] : 0.0f;
    }
}

// ---------------------------------------------------------------------------
extern "C" void kernel_launch(void* const* d_in, const int* in_sizes, int n_in,
                              void* d_out, int out_size, void* d_ws, size_t ws_size,
                              hipStream_t stream)
{
    const float* x    = (const float*)d_in[0];
    const float* W    = (const float*)d_in[1];
    const float* bias = (const float*)d_in[2];
    float* out  = (float*)d_out;
    float* zbuf = (float*)d_ws;

    const size_t row_bytes = (size_t)N_RFF * sizeof(float);
    const size_t maxrows   = row_bytes ? (ws_size / row_bytes) : 0;

    int chunk = (maxrows >= (size_t)M_TOTAL) ? M_TOTAL : (int)maxrows;
    if (chunk < 1) chunk = 1;

    for (int m0 = 0; m0 < M_TOTAL; m0 += chunk) {
        int rows = M_TOTAL - m0;
        if (rows > chunk) rows = chunk;
        dim3 gg(N_RFF / BN, (rows + BM - 1) / BM);
        hipLaunchKernelGGL(rff_gemm_chain, gg, dim3(256), 0, stream,
                           x, W, bias, zbuf, m0, rows);
        hipLaunchKernelGGL(topk_select, dim3(rows), dim3(256), 0, stream,
                           zbuf, out, m0);
    }
}